// Round 1
// baseline (936.113 us; speedup 1.0000x reference)
//
#include <hip/hip_runtime.h>

typedef unsigned short u16;
typedef unsigned int u32;
typedef short bf16x8 __attribute__((ext_vector_type(8)));
typedef float f32x4 __attribute__((ext_vector_type(4)));

__device__ __forceinline__ u16 f2bf(float f) {
    u32 u = __float_as_uint(f);
    u32 r = (u + 0x7fffu + ((u >> 16) & 1u)) >> 16;
    return (u16)r;
}
__device__ __forceinline__ float bf2f(u16 v) { return __uint_as_float(((u32)v) << 16); }
__device__ __forceinline__ float bflo(u32 u) { return __uint_as_float(u << 16); }
__device__ __forceinline__ float bfhi(u32 u) { return __uint_as_float(u & 0xffff0000u); }

// async global->LDS, 16B per lane. LDS dest must be wave-uniform base + lane*16.
__device__ __forceinline__ void load_lds16(const void* g, void* l) {
    __builtin_amdgcn_global_load_lds(
        (const __attribute__((address_space(1))) void*)(unsigned long long)g,
        (__attribute__((address_space(3))) void*)(u32)(unsigned long long)l,
        16, 0, 0);
}

// ---------------------------------------------------------------------------
// k_w: fold LoRA into transposed bf16 weights.
// WqkvT[n][k] = W_qkv[k][n] + (n<1024: 2*Aq@Bq) (n>=2048: 2*Av@Bv)
// WprojT[n][k] = W_proj[k][n] + 2*Ap@Bp
// ---------------------------------------------------------------------------
__global__ __launch_bounds__(256) void k_w(
    const float* __restrict__ Wqkv,
    const float* __restrict__ Aq, const float* __restrict__ Bq,
    const float* __restrict__ Av, const float* __restrict__ Bv,
    const float* __restrict__ Wp, const float* __restrict__ Ap,
    const float* __restrict__ Bp,
    u16* __restrict__ WqkvT, u16* __restrict__ WprojT)
{
    int e = blockIdx.x * 256 + threadIdx.x;
    if (e < 3145728) {                       // 1024 * 3072
        int k = e / 3072;
        int n = e - k * 3072;
        float w = Wqkv[e];
        if (n < 1024) {
            float d = 0.f;
#pragma unroll
            for (int r = 0; r < 8; ++r) d += Aq[k * 8 + r] * Bq[r * 1024 + n];
            w += 2.f * d;
        } else if (n >= 2048) {
            int n2 = n - 2048;
            float d = 0.f;
#pragma unroll
            for (int r = 0; r < 8; ++r) d += Av[k * 8 + r] * Bv[r * 1024 + n2];
            w += 2.f * d;
        }
        WqkvT[(size_t)n * 1024 + k] = f2bf(w);
    } else {
        int e2 = e - 3145728;                // 1024 * 1024
        int k = e2 >> 10, n = e2 & 1023;
        float d = 0.f;
#pragma unroll
        for (int r = 0; r < 8; ++r) d += Ap[k * 8 + r] * Bp[r * 1024 + n];
        WprojT[(size_t)n * 1024 + k] = f2bf(Wp[e2] + 2.f * d);
    }
}

// ---------------------------------------------------------------------------
// k0: xb = bf16(x + temporal_pos), [65536][1024]
// ---------------------------------------------------------------------------
__global__ __launch_bounds__(256) void k0_prep(
    const float* __restrict__ x, const float* __restrict__ tpos,
    u16* __restrict__ xb)
{
    size_t idx = ((size_t)blockIdx.x * 256 + threadIdx.x) * 8;
    int col = (int)(idx & 1023);
    int t = (int)((idx >> 10) & 3);
    const float4* xp = (const float4*)(x + idx);
    const float4* tp = (const float4*)(tpos + t * 1024 + col);
    float4 a0 = xp[0], a1 = xp[1];
    float4 b0 = tp[0], b1 = tp[1];
    u32 p0 = (u32)f2bf(a0.x + b0.x) | ((u32)f2bf(a0.y + b0.y) << 16);
    u32 p1 = (u32)f2bf(a0.z + b0.z) | ((u32)f2bf(a0.w + b0.w) << 16);
    u32 p2 = (u32)f2bf(a1.x + b1.x) | ((u32)f2bf(a1.y + b1.y) << 16);
    u32 p3 = (u32)f2bf(a1.z + b1.z) | ((u32)f2bf(a1.w + b1.w) << 16);
    *(uint4*)(xb + idx) = make_uint4(p0, p1, p2, p3);
}

// ---------------------------------------------------------------------------
// k1: per block: 128 rows (32 b's) x one head h.
//   GEMM: [128 x 1024] x [1024 x 192] (Q|K|V strips of W_qkvT) -> LDS
//   then 4-wide attention + mean over t -> obar[16384][1024] bf16
// LDS staging: A 1024 chunks(16B), B 1536 chunks; XOR-swizzle chunk-in-row.
// ---------------------------------------------------------------------------
__global__ __launch_bounds__(256) void k1_qkv_attn(
    const u16* __restrict__ xb, const u16* __restrict__ WqkvT,
    u16* __restrict__ obar)
{
    __shared__ __align__(16) char smem[53760];
    u16* stage = (u16*)smem;                 // staging: A at 0, B at 16384B
    u16* qkv = (u16*)smem;                   // epilogue overlay: [128][200]
    float* S = (float*)(smem + 51200);       // [32][16]
    float* wP = (float*)(smem + 53248);      // [32][4]

    const int tid = threadIdx.x;
    const int lane = tid & 63;
    const int wid = tid >> 6;
    const int wm = wid & 1;                  // 2x2 wave grid: wave = 64 x 96
    const int wn = wid >> 1;
    const int lm = lane & 15;
    const int lk = lane >> 4;
    const int h = blockIdx.x;                // 0..15
    const int mt = blockIdx.y;               // 0..511

    // staging source offsets (elements) at k0 = 0
    u32 goff[10];
#pragma unroll
    for (int i = 0; i < 10; ++i) {
        int c = i * 256 + tid;
        if (i < 4) {                         // A: chunks 0..1023
            int row = c >> 3, cc = c & 7;
            int cc2 = cc ^ (row & 7);
            goff[i] = (u32)((mt * 128 + row) * 1024 + cc2 * 8);
        } else {                             // B: chunks 0..1535
            int cb = c - 1024;
            int n = cb >> 3, cc = cb & 7;
            int cc2 = cc ^ (n & 7);
            int strip = n >> 6, j = n & 63;
            goff[i] = (u32)(((strip << 10) + h * 64 + j) * 1024 + cc2 * 8);
        }
    }

    f32x4 acc[4][6];
#pragma unroll
    for (int a = 0; a < 4; ++a)
#pragma unroll
        for (int b = 0; b < 6; ++b) acc[a][b] = (f32x4){0.f, 0.f, 0.f, 0.f};

    for (int kt = 0; kt < 16; ++kt) {
        const int k0 = kt * 64;
        __syncthreads();
#pragma unroll
        for (int i = 0; i < 10; ++i) {
            const u16* g = (i < 4 ? xb : WqkvT) + goff[i] + k0;
            load_lds16((const void*)g, (void*)(smem + i * 4096 + tid * 16));
        }
        __syncthreads();
#pragma unroll
        for (int kk = 0; kk < 2; ++kk) {
            const int kb = kk * 4 + lk;
            bf16x8 af[4], bfr[6];
#pragma unroll
            for (int im = 0; im < 4; ++im) {
                int m = wm * 64 + im * 16 + lm;
                af[im] = *(const bf16x8*)(stage + (m * 8 + (kb ^ (m & 7))) * 8);
            }
#pragma unroll
            for (int in = 0; in < 6; ++in) {
                int n = wn * 96 + in * 16 + lm;
                bfr[in] = *(const bf16x8*)(stage + 8192 + (n * 8 + (kb ^ (n & 7))) * 8);
            }
#pragma unroll
            for (int im = 0; im < 4; ++im)
#pragma unroll
                for (int in = 0; in < 6; ++in)
                    acc[im][in] = __builtin_amdgcn_mfma_f32_16x16x32_bf16(
                        af[im], bfr[in], acc[im][in], 0, 0, 0);
        }
    }

    __syncthreads();
    // C frags -> qkv LDS (bf16). C/D layout: col = lane&15, row = (lane>>4)*4 + r
#pragma unroll
    for (int im = 0; im < 4; ++im) {
#pragma unroll
        for (int in = 0; in < 6; ++in) {
            int col = wn * 96 + in * 16 + lm;
            int rowb = wm * 64 + im * 16 + lk * 4;
#pragma unroll
            for (int r = 0; r < 4; ++r)
                qkv[(rowb + r) * 200 + col] = f2bf(acc[im][in][r]);
        }
    }
    __syncthreads();

    // S[bl][t][u] = 0.125 * dot(Q[4bl+t], K[4bl+u]);  512 tasks, 2/thread
#pragma unroll
    for (int it = 0; it < 2; ++it) {
        int task = tid + it * 256;
        int bl = task >> 4, t = (task >> 2) & 3, u = task & 3;
        const u32* q4 = (const u32*)(qkv + (bl * 4 + t) * 200);
        const u32* k4 = (const u32*)(qkv + (bl * 4 + u) * 200 + 64);
        float s = 0.f;
#pragma unroll
        for (int d = 0; d < 32; ++d) {
            u32 qa = q4[d], ka = k4[d];
            s += bflo(qa) * bflo(ka) + bfhi(qa) * bfhi(ka);
        }
        S[bl * 16 + t * 4 + u] = s * 0.125f;
    }
    __syncthreads();
    // softmax per (bl,t), store P/4
    if (tid < 128) {
        float* sp = S + (tid >> 2) * 16 + (tid & 3) * 4;
        float s0 = sp[0], s1 = sp[1], s2 = sp[2], s3 = sp[3];
        float mx = fmaxf(fmaxf(s0, s1), fmaxf(s2, s3));
        float e0 = __expf(s0 - mx), e1 = __expf(s1 - mx);
        float e2 = __expf(s2 - mx), e3 = __expf(s3 - mx);
        float inv = 0.25f / (e0 + e1 + e2 + e3);
        sp[0] = e0 * inv; sp[1] = e1 * inv; sp[2] = e2 * inv; sp[3] = e3 * inv;
    }
    __syncthreads();
    // w[bl][u] = sum_t P[t][u]/4   (mean over t commutes with P@V)
    if (tid < 128) {
        int bl = tid >> 2, u = tid & 3;
        wP[bl * 4 + u] = S[bl * 16 + u] + S[bl * 16 + 4 + u] +
                         S[bl * 16 + 8 + u] + S[bl * 16 + 12 + u];
    }
    __syncthreads();
    // obar[b][h*64+d] = sum_u w[u] * V[4b+u][d];  thread -> (bl, 8 d's)
    {
        int bl = tid >> 3, db = (tid & 7) * 8;
        float w0 = wP[bl * 4 + 0], w1 = wP[bl * 4 + 1];
        float w2 = wP[bl * 4 + 2], w3 = wP[bl * 4 + 3];
        const u16* v0 = qkv + (bl * 4 + 0) * 200 + 128 + db;
        const u16* v1 = v0 + 200;
        const u16* v2 = v1 + 200;
        const u16* v3 = v2 + 200;
        u16 ov[8];
#pragma unroll
        for (int j = 0; j < 8; ++j) {
            float val = w0 * bf2f(v0[j]) + w1 * bf2f(v1[j]) +
                        w2 * bf2f(v2[j]) + w3 * bf2f(v3[j]);
            ov[j] = f2bf(val);
        }
        u32 p0 = (u32)ov[0] | ((u32)ov[1] << 16);
        u32 p1 = (u32)ov[2] | ((u32)ov[3] << 16);
        u32 p2 = (u32)ov[4] | ((u32)ov[5] << 16);
        u32 p3 = (u32)ov[6] | ((u32)ov[7] << 16);
        size_t brow = (size_t)mt * 32 + bl;
        *(uint4*)(obar + brow * 1024 + h * 64 + db) = make_uint4(p0, p1, p2, p3);
    }
}

// ---------------------------------------------------------------------------
// k2: out = obar @ WprojT^T + bias  ([16384,1024] x [1024,1024], fp32 out)
// BM=BN=128, BK=64, 2x2 waves of 64x64.
// ---------------------------------------------------------------------------
__global__ __launch_bounds__(256) void k2_proj(
    const u16* __restrict__ obar, const u16* __restrict__ WprojT,
    const float* __restrict__ bias, float* __restrict__ out)
{
    __shared__ __align__(16) char smem[32768];
    u16* stage = (u16*)smem;
    const int tid = threadIdx.x;
    const int lane = tid & 63;
    const int wid = tid >> 6;
    const int wm = wid & 1, wn = wid >> 1;
    const int lm = lane & 15, lk = lane >> 4;
    const int nt = blockIdx.x;               // 0..7
    const int mt = blockIdx.y;               // 0..127

    u32 goff[8];
#pragma unroll
    for (int i = 0; i < 8; ++i) {
        int c = i * 256 + tid;
        if (i < 4) {
            int row = c >> 3, cc2 = (c & 7) ^ (row & 7);
            goff[i] = (u32)((mt * 128 + row) * 1024 + cc2 * 8);
        } else {
            int cb = c - 1024;
            int n = cb >> 3, cc2 = (cb & 7) ^ (n & 7);
            goff[i] = (u32)((nt * 128 + n) * 1024 + cc2 * 8);
        }
    }

    f32x4 acc[4][4];
#pragma unroll
    for (int a = 0; a < 4; ++a)
#pragma unroll
        for (int b = 0; b < 4; ++b) acc[a][b] = (f32x4){0.f, 0.f, 0.f, 0.f};

    for (int kt = 0; kt < 16; ++kt) {
        const int k0 = kt * 64;
        __syncthreads();
#pragma unroll
        for (int i = 0; i < 8; ++i) {
            const u16* g = (i < 4 ? obar : WprojT) + goff[i] + k0;
            load_lds16((const void*)g, (void*)(smem + i * 4096 + tid * 16));
        }
        __syncthreads();
#pragma unroll
        for (int kk = 0; kk < 2; ++kk) {
            const int kb = kk * 4 + lk;
            bf16x8 af[4], bfr[4];
#pragma unroll
            for (int im = 0; im < 4; ++im) {
                int m = wm * 64 + im * 16 + lm;
                af[im] = *(const bf16x8*)(stage + (m * 8 + (kb ^ (m & 7))) * 8);
            }
#pragma unroll
            for (int in = 0; in < 4; ++in) {
                int n = wn * 64 + in * 16 + lm;
                bfr[in] = *(const bf16x8*)(stage + 8192 + (n * 8 + (kb ^ (n & 7))) * 8);
            }
#pragma unroll
            for (int im = 0; im < 4; ++im)
#pragma unroll
                for (int in = 0; in < 4; ++in)
                    acc[im][in] = __builtin_amdgcn_mfma_f32_16x16x32_bf16(
                        af[im], bfr[in], acc[im][in], 0, 0, 0);
        }
    }

    float bv[4];
#pragma unroll
    for (int in = 0; in < 4; ++in) bv[in] = bias[nt * 128 + wn * 64 + in * 16 + lm];
#pragma unroll
    for (int im = 0; im < 4; ++im)
#pragma unroll
        for (int in = 0; in < 4; ++in) {
            int col = nt * 128 + wn * 64 + in * 16 + lm;
#pragma unroll
            for (int r = 0; r < 4; ++r) {
                int row = mt * 128 + wm * 64 + im * 16 + lk * 4 + r;
                out[(size_t)row * 1024 + col] = acc[im][in][r] + bv[in];
            }
        }
}

// ---------------------------------------------------------------------------
extern "C" void kernel_launch(void* const* d_in, const int* in_sizes, int n_in,
                              void* d_out, int out_size, void* d_ws, size_t ws_size,
                              hipStream_t stream)
{
    const float* x     = (const float*)d_in[0];
    const float* tpos  = (const float*)d_in[1];
    const float* Wqkv  = (const float*)d_in[2];
    const float* Aq    = (const float*)d_in[3];
    const float* Bq    = (const float*)d_in[4];
    const float* Av    = (const float*)d_in[5];
    const float* Bv    = (const float*)d_in[6];
    const float* Wp    = (const float*)d_in[7];
    const float* bp    = (const float*)d_in[8];
    const float* Ap    = (const float*)d_in[9];
    const float* Bp    = (const float*)d_in[10];
    float* out = (float*)d_out;

    char* ws = (char*)d_ws;
    u16* xb     = (u16*)ws;                                  // 134,217,728 B
    u16* obar   = (u16*)(ws + 134217728);                    //  33,554,432 B
    u16* WqkvT  = (u16*)(ws + 134217728 + 33554432);         //   6,291,456 B
    u16* WprojT = (u16*)(ws + 134217728 + 33554432 + 6291456); // 2,097,152 B

    hipLaunchKernelGGL(k_w, dim3(16384), dim3(256), 0, stream,
                       Wqkv, Aq, Bq, Av, Bv, Wp, Ap, Bp, WqkvT, WprojT);
    hipLaunchKernelGGL(k0_prep, dim3(32768), dim3(256), 0, stream, x, tpos, xb);
    hipLaunchKernelGGL(k1_qkv_attn, dim3(16, 512), dim3(256), 0, stream,
                       xb, WqkvT, obar);
    hipLaunchKernelGGL(k2_proj, dim3(8, 128), dim3(256), 0, stream,
                       obar, WprojT, bp, out);
}

// Round 2
// 875.121 us; speedup vs baseline: 1.0697x; 1.0697x over previous
//
#include <hip/hip_runtime.h>

typedef unsigned short u16;
typedef unsigned int u32;
typedef short bf16x8 __attribute__((ext_vector_type(8)));
typedef float f32x4 __attribute__((ext_vector_type(4)));

__device__ __forceinline__ u16 f2bf(float f) {
    u32 u = __float_as_uint(f);
    u32 r = (u + 0x7fffu + ((u >> 16) & 1u)) >> 16;
    return (u16)r;
}
__device__ __forceinline__ float bf2f(u16 v) { return __uint_as_float(((u32)v) << 16); }
__device__ __forceinline__ float bflo(u32 u) { return __uint_as_float(u << 16); }
__device__ __forceinline__ float bfhi(u32 u) { return __uint_as_float(u & 0xffff0000u); }

__device__ __forceinline__ void load_lds16(const void* g, void* l) {
    __builtin_amdgcn_global_load_lds(
        (const __attribute__((address_space(1))) void*)(unsigned long long)g,
        (__attribute__((address_space(3))) void*)(u32)(unsigned long long)l,
        16, 0, 0);
}

// ---------------------------------------------------------------------------
// k_w: fold LoRA into transposed bf16 weights, coalesced writes via LDS tile.
// blocks 0..767: Wqkv 64x64 tiles (16 kt x 48 nt); 768..1023: Wproj tiles.
// ---------------------------------------------------------------------------
__global__ __launch_bounds__(256) void k_w(
    const float* __restrict__ Wqkv,
    const float* __restrict__ Aq, const float* __restrict__ Bq,
    const float* __restrict__ Av, const float* __restrict__ Bv,
    const float* __restrict__ Wp, const float* __restrict__ Ap,
    const float* __restrict__ Bp,
    u16* __restrict__ WqkvT, u16* __restrict__ WprojT)
{
    __shared__ float As[512];        // [64][8]  lora A tile
    __shared__ float Bs[512];        // [8][64]  lora B tile
    __shared__ float T[64 * 65];     // [n_local][k_local + pad]

    const int tid = threadIdx.x;
    const int b = blockIdx.x;

    const float* W; const float* Ax = nullptr; const float* Bx = nullptr;
    u16* Wout; int ldw, k0, n0, nB = 0;
    bool has_lora;
    if (b < 768) {
        int kt = b / 48, ntile = b - kt * 48;
        k0 = kt * 64; n0 = ntile * 64;
        W = Wqkv; ldw = 3072; Wout = WqkvT;
        if (n0 < 1024)       { has_lora = true;  Ax = Aq; Bx = Bq; nB = n0; }
        else if (n0 >= 2048) { has_lora = true;  Ax = Av; Bx = Bv; nB = n0 - 2048; }
        else                 { has_lora = false; }
    } else {
        int b2 = b - 768;
        int kt = b2 >> 4, ntile = b2 & 15;
        k0 = kt * 64; n0 = ntile * 64;
        W = Wp; ldw = 1024; Wout = WprojT;
        has_lora = true; Ax = Ap; Bx = Bp; nB = n0;
    }

    if (has_lora) {
#pragma unroll
        for (int it = 0; it < 2; ++it) {
            int idx = tid + it * 256;
            As[idx] = Ax[(k0 + (idx >> 3)) * 8 + (idx & 7)];
            Bs[idx] = Bx[(idx >> 6) * 1024 + nB + (idx & 63)];
        }
    }
    __syncthreads();

    const int r8 = tid >> 3;         // 0..31
    const int c = tid & 7;           // 0..7 (8-col group)
#pragma unroll
    for (int it = 0; it < 2; ++it) {
        int kl = r8 + it * 32;
        const float* wrow = W + (size_t)(k0 + kl) * ldw + n0 + c * 8;
        float4 w0 = *(const float4*)wrow;
        float4 w1 = *(const float4*)(wrow + 4);
        float wv[8] = {w0.x, w0.y, w0.z, w0.w, w1.x, w1.y, w1.z, w1.w};
        if (has_lora) {
#pragma unroll
            for (int j = 0; j < 8; ++j) {
                float d = 0.f;
#pragma unroll
                for (int r = 0; r < 8; ++r) d += As[kl * 8 + r] * Bs[r * 64 + c * 8 + j];
                wv[j] += 2.f * d;
            }
        }
#pragma unroll
        for (int j = 0; j < 8; ++j) T[(c * 8 + j) * 65 + kl] = wv[j];
    }
    __syncthreads();

#pragma unroll
    for (int it = 0; it < 2; ++it) {
        int nl = r8 + it * 32;
        u16 o[8];
#pragma unroll
        for (int j = 0; j < 8; ++j) o[j] = f2bf(T[nl * 65 + c * 8 + j]);
        u32 p0 = (u32)o[0] | ((u32)o[1] << 16);
        u32 p1 = (u32)o[2] | ((u32)o[3] << 16);
        u32 p2 = (u32)o[4] | ((u32)o[5] << 16);
        u32 p3 = (u32)o[6] | ((u32)o[7] << 16);
        *(uint4*)(Wout + (size_t)(n0 + nl) * 1024 + k0 + c * 8) =
            make_uint4(p0, p1, p2, p3);
    }
}

// ---------------------------------------------------------------------------
// k0: xb = bf16(x + temporal_pos), [65536][1024]
// ---------------------------------------------------------------------------
__global__ __launch_bounds__(256) void k0_prep(
    const float* __restrict__ x, const float* __restrict__ tpos,
    u16* __restrict__ xb)
{
    size_t idx = ((size_t)blockIdx.x * 256 + threadIdx.x) * 8;
    int col = (int)(idx & 1023);
    int t = (int)((idx >> 10) & 3);
    const float4* xp = (const float4*)(x + idx);
    const float4* tp = (const float4*)(tpos + t * 1024 + col);
    float4 a0 = xp[0], a1 = xp[1];
    float4 b0 = tp[0], b1 = tp[1];
    u32 p0 = (u32)f2bf(a0.x + b0.x) | ((u32)f2bf(a0.y + b0.y) << 16);
    u32 p1 = (u32)f2bf(a0.z + b0.z) | ((u32)f2bf(a0.w + b0.w) << 16);
    u32 p2 = (u32)f2bf(a1.x + b1.x) | ((u32)f2bf(a1.y + b1.y) << 16);
    u32 p3 = (u32)f2bf(a1.z + b1.z) | ((u32)f2bf(a1.w + b1.w) << 16);
    *(uint4*)(xb + idx) = make_uint4(p0, p1, p2, p3);
}

// ---------------------------------------------------------------------------
// k1 v2: 512 threads, 8 waves (4m x 2n of 32x96), BM=128 BN=192 BK=64.
// acc = 48 regs/lane (was 96) -> target 4 waves/SIMD.
// ---------------------------------------------------------------------------
__global__ __launch_bounds__(512, 4) void k1_qkv_attn(
    const u16* __restrict__ xb, const u16* __restrict__ WqkvT,
    u16* __restrict__ obar)
{
    __shared__ __align__(16) char smem[52224];
    u16* stage = (u16*)smem;                 // staging: A at 0, B at 16384B
    u16* qkv = (u16*)smem;                   // epilogue overlay: [128][194]
    float* S = (float*)(smem + 49664);       // [32][16]
    float* wP = (float*)(smem + 51712);      // [32][4]

    const int tid = threadIdx.x;
    const int lane = tid & 63;
    const int wid = tid >> 6;                // 0..7
    const int wm = wid & 3;                  // m-base = wm*32
    const int wn = wid >> 2;                 // n-base = wn*96
    const int lm = lane & 15;
    const int lk = lane >> 4;
    const int h = blockIdx.x;                // 0..15
    const int mt = blockIdx.y;               // 0..511

    // staging source offsets (elements) at k0 = 0; 5 chunks of 16B per thread
    u32 goff[5];
#pragma unroll
    for (int i = 0; i < 5; ++i) {
        int c = i * 512 + tid;
        if (c < 1024) {                      // A chunks (uniform per i)
            int row = c >> 3, cc2 = (c & 7) ^ (row & 7);
            goff[i] = (u32)((mt * 128 + row) * 1024 + cc2 * 8);
        } else {                             // B chunks
            int cb = c - 1024;
            int n = cb >> 3, cc2 = (cb & 7) ^ (n & 7);
            int strip = n >> 6, j = n & 63;
            goff[i] = (u32)(((strip << 10) + h * 64 + j) * 1024 + cc2 * 8);
        }
    }

    f32x4 acc[2][6];
#pragma unroll
    for (int a = 0; a < 2; ++a)
#pragma unroll
        for (int bb = 0; bb < 6; ++bb) acc[a][bb] = (f32x4){0.f, 0.f, 0.f, 0.f};

    for (int kt = 0; kt < 16; ++kt) {
        const int k0 = kt * 64;
        __syncthreads();
#pragma unroll
        for (int i = 0; i < 5; ++i) {
            const u16* g = (i < 2 ? xb : WqkvT) + goff[i] + k0;
            load_lds16((const void*)g, (void*)(smem + i * 8192 + tid * 16));
        }
        __syncthreads();
#pragma unroll
        for (int kk = 0; kk < 2; ++kk) {
            const int kb = kk * 4 + lk;
            bf16x8 af[2], bfr[6];
#pragma unroll
            for (int im = 0; im < 2; ++im) {
                int m = wm * 32 + im * 16 + lm;
                af[im] = *(const bf16x8*)(stage + (m * 8 + (kb ^ (m & 7))) * 8);
            }
#pragma unroll
            for (int in = 0; in < 6; ++in) {
                int n = wn * 96 + in * 16 + lm;
                bfr[in] = *(const bf16x8*)(stage + 8192 + (n * 8 + (kb ^ (n & 7))) * 8);
            }
#pragma unroll
            for (int im = 0; im < 2; ++im)
#pragma unroll
                for (int in = 0; in < 6; ++in)
                    acc[im][in] = __builtin_amdgcn_mfma_f32_16x16x32_bf16(
                        af[im], bfr[in], acc[im][in], 0, 0, 0);
        }
    }

    __syncthreads();
    // C frags -> qkv LDS (bf16). C/D layout: col = lane&15, row = (lane>>4)*4 + r
#pragma unroll
    for (int im = 0; im < 2; ++im) {
#pragma unroll
        for (int in = 0; in < 6; ++in) {
            int col = wn * 96 + in * 16 + lm;
            int rowb = wm * 32 + im * 16 + lk * 4;
#pragma unroll
            for (int r = 0; r < 4; ++r)
                qkv[(rowb + r) * 194 + col] = f2bf(acc[im][in][r]);
        }
    }
    __syncthreads();

    // S[bl][t][u] = 0.125 * dot(Q[4bl+t], K[4bl+u]);  512 tasks, 1/thread
    {
        int bl = tid >> 4, t = (tid >> 2) & 3, u = tid & 3;
        const u32* q4 = (const u32*)(qkv + (bl * 4 + t) * 194);
        const u32* k4 = (const u32*)(qkv + (bl * 4 + u) * 194 + 64);
        float s = 0.f;
#pragma unroll
        for (int d = 0; d < 32; ++d) {
            u32 qa = q4[d], ka = k4[d];
            s += bflo(qa) * bflo(ka) + bfhi(qa) * bfhi(ka);
        }
        S[bl * 16 + t * 4 + u] = s * 0.125f;
    }
    __syncthreads();
    // softmax per (bl,t), store P/4
    if (tid < 128) {
        float* sp = S + (tid >> 2) * 16 + (tid & 3) * 4;
        float s0 = sp[0], s1 = sp[1], s2 = sp[2], s3 = sp[3];
        float mx = fmaxf(fmaxf(s0, s1), fmaxf(s2, s3));
        float e0 = __expf(s0 - mx), e1 = __expf(s1 - mx);
        float e2 = __expf(s2 - mx), e3 = __expf(s3 - mx);
        float inv = 0.25f / (e0 + e1 + e2 + e3);
        sp[0] = e0 * inv; sp[1] = e1 * inv; sp[2] = e2 * inv; sp[3] = e3 * inv;
    }
    __syncthreads();
    // w[bl][u] = sum_t P[t][u]/4
    if (tid < 128) {
        int bl = tid >> 2, u = tid & 3;
        wP[bl * 4 + u] = S[bl * 16 + u] + S[bl * 16 + 4 + u] +
                         S[bl * 16 + 8 + u] + S[bl * 16 + 12 + u];
    }
    __syncthreads();
    // obar[b][h*64+d] = sum_u w[u] * V[4b+u][d]
    if (tid < 256) {
        int bl = tid >> 3, db = (tid & 7) * 8;
        float w0 = wP[bl * 4 + 0], w1 = wP[bl * 4 + 1];
        float w2 = wP[bl * 4 + 2], w3 = wP[bl * 4 + 3];
        const u16* v0 = qkv + (bl * 4 + 0) * 194 + 128 + db;
        const u16* v1 = v0 + 194;
        const u16* v2 = v1 + 194;
        const u16* v3 = v2 + 194;
        u16 ov[8];
#pragma unroll
        for (int j = 0; j < 8; ++j) {
            float val = w0 * bf2f(v0[j]) + w1 * bf2f(v1[j]) +
                        w2 * bf2f(v2[j]) + w3 * bf2f(v3[j]);
            ov[j] = f2bf(val);
        }
        u32 p0 = (u32)ov[0] | ((u32)ov[1] << 16);
        u32 p1 = (u32)ov[2] | ((u32)ov[3] << 16);
        u32 p2 = (u32)ov[4] | ((u32)ov[5] << 16);
        u32 p3 = (u32)ov[6] | ((u32)ov[7] << 16);
        size_t brow = (size_t)mt * 32 + bl;
        *(uint4*)(obar + brow * 1024 + h * 64 + db) = make_uint4(p0, p1, p2, p3);
    }
}

// ---------------------------------------------------------------------------
// k2: out = obar @ WprojT^T + bias  ([16384,1024] x [1024,1024], fp32 out)
// ---------------------------------------------------------------------------
__global__ __launch_bounds__(256) void k2_proj(
    const u16* __restrict__ obar, const u16* __restrict__ WprojT,
    const float* __restrict__ bias, float* __restrict__ out)
{
    __shared__ __align__(16) char smem[32768];
    u16* stage = (u16*)smem;
    const int tid = threadIdx.x;
    const int lane = tid & 63;
    const int wid = tid >> 6;
    const int wm = wid & 1, wn = wid >> 1;
    const int lm = lane & 15, lk = lane >> 4;
    const int nt = blockIdx.x;               // 0..7
    const int mt = blockIdx.y;               // 0..127

    u32 goff[8];
#pragma unroll
    for (int i = 0; i < 8; ++i) {
        int c = i * 256 + tid;
        if (i < 4) {
            int row = c >> 3, cc2 = (c & 7) ^ (row & 7);
            goff[i] = (u32)((mt * 128 + row) * 1024 + cc2 * 8);
        } else {
            int cb = c - 1024;
            int n = cb >> 3, cc2 = (cb & 7) ^ (n & 7);
            goff[i] = (u32)((nt * 128 + n) * 1024 + cc2 * 8);
        }
    }

    f32x4 acc[4][4];
#pragma unroll
    for (int a = 0; a < 4; ++a)
#pragma unroll
        for (int bb = 0; bb < 4; ++bb) acc[a][bb] = (f32x4){0.f, 0.f, 0.f, 0.f};

    for (int kt = 0; kt < 16; ++kt) {
        const int k0 = kt * 64;
        __syncthreads();
#pragma unroll
        for (int i = 0; i < 8; ++i) {
            const u16* g = (i < 4 ? obar : WprojT) + goff[i] + k0;
            load_lds16((const void*)g, (void*)(smem + i * 4096 + tid * 16));
        }
        __syncthreads();
#pragma unroll
        for (int kk = 0; kk < 2; ++kk) {
            const int kb = kk * 4 + lk;
            bf16x8 af[4], bfr[4];
#pragma unroll
            for (int im = 0; im < 4; ++im) {
                int m = wm * 64 + im * 16 + lm;
                af[im] = *(const bf16x8*)(stage + (m * 8 + (kb ^ (m & 7))) * 8);
            }
#pragma unroll
            for (int in = 0; in < 4; ++in) {
                int n = wn * 64 + in * 16 + lm;
                bfr[in] = *(const bf16x8*)(stage + 8192 + (n * 8 + (kb ^ (n & 7))) * 8);
            }
#pragma unroll
            for (int im = 0; im < 4; ++im)
#pragma unroll
                for (int in = 0; in < 4; ++in)
                    acc[im][in] = __builtin_amdgcn_mfma_f32_16x16x32_bf16(
                        af[im], bfr[in], acc[im][in], 0, 0, 0);
        }
    }

    float bv[4];
#pragma unroll
    for (int in = 0; in < 4; ++in) bv[in] = bias[nt * 128 + wn * 64 + in * 16 + lm];
#pragma unroll
    for (int im = 0; im < 4; ++im)
#pragma unroll
        for (int in = 0; in < 4; ++in) {
            int col = nt * 128 + wn * 64 + in * 16 + lm;
#pragma unroll
            for (int r = 0; r < 4; ++r) {
                int row = mt * 128 + wm * 64 + im * 16 + lk * 4 + r;
                out[(size_t)row * 1024 + col] = acc[im][in][r] + bv[in];
            }
        }
}

// ---------------------------------------------------------------------------
extern "C" void kernel_launch(void* const* d_in, const int* in_sizes, int n_in,
                              void* d_out, int out_size, void* d_ws, size_t ws_size,
                              hipStream_t stream)
{
    const float* x     = (const float*)d_in[0];
    const float* tpos  = (const float*)d_in[1];
    const float* Wqkv  = (const float*)d_in[2];
    const float* Aq    = (const float*)d_in[3];
    const float* Bq    = (const float*)d_in[4];
    const float* Av    = (const float*)d_in[5];
    const float* Bv    = (const float*)d_in[6];
    const float* Wp    = (const float*)d_in[7];
    const float* bp    = (const float*)d_in[8];
    const float* Ap    = (const float*)d_in[9];
    const float* Bp    = (const float*)d_in[10];
    float* out = (float*)d_out;

    char* ws = (char*)d_ws;
    u16* xb     = (u16*)ws;                                    // 134,217,728 B
    u16* obar   = (u16*)(ws + 134217728);                      //  33,554,432 B
    u16* WqkvT  = (u16*)(ws + 134217728 + 33554432);           //   6,291,456 B
    u16* WprojT = (u16*)(ws + 134217728 + 33554432 + 6291456); //  2,097,152 B

    hipLaunchKernelGGL(k_w, dim3(1024), dim3(256), 0, stream,
                       Wqkv, Aq, Bq, Av, Bv, Wp, Ap, Bp, WqkvT, WprojT);
    hipLaunchKernelGGL(k0_prep, dim3(32768), dim3(256), 0, stream, x, tpos, xb);
    hipLaunchKernelGGL(k1_qkv_attn, dim3(16, 512), dim3(512), 0, stream,
                       xb, WqkvT, obar);
    hipLaunchKernelGGL(k2_proj, dim3(8, 128), dim3(256), 0, stream,
                       obar, WprojT, bp, out);
}